// Round 7
// baseline (3686.278 us; speedup 1.0000x reference)
//
#include <hip/hip_runtime.h>
#include <math.h>

// 2-layer LSTM (H=512), T=1024 teacher steps + 64 AR steps; only batch row 255
// reaches the output -> single-sequence LSTM. Weights register-resident across
// 64 persistent WGs. Per-tick all-to-all h exchange via SELF-VALIDATING pairs:
// each published value is a u64 (gen<<32 | bitcast(h)); a WG's line is 16
// pairs = 128 B. Producers: relaxed agent-scope b64 atomic stores. Consumers:
// all 512 threads spin on relaxed b64 atomic loads (8 lanes/line, 2 pairs/
// lane) until gen fields == g -> detection and data in ONE IC round-trip.
// 8B atomicity forbids torn reads; slot-reuse safe by barrier-ordered
// value-dependency causality (a producer overwrites gen g-1 pairs only after
// its WG's barrier for gen g, which requires every WG to have published gen g,
// which requires their gen g-1 reads to have completed).
//
// R7 restructure: wave rg owns L1 unit wg*8+rg AND L2 unit wg*8+rg (rows
// q*8+rg). After the in-wave shuffle reduce-scatter each wave applies its own
// gates (lanes 0/1 hold c1/c2) and publishes its own 2 pairs -> ONE
// __syncthreads per tick, no wave-0 funnel, publish fires per-wave.
// computeO (AR feedback scalar) computed redundantly per wave (no sync).
// hvec double-buffered by tick parity (wave skew <= 1 tick across the single
// barrier). Chunk stride 264 words to de-alias LDS banks.

#define G     64      // workgroups
#define NT    512     // threads/wg
#define HD    512     // hidden
#define TT    1024    // teacher steps
#define PRED  64      // prediction length
#define LINEF 64      // floats per comm line slot (256 B); pairs in words 0..31
#define SLOTF (G*LINEF)
#define STR   264     // hvec chunk stride in words (256 data + 8 pad banks)
#define HVS   (4*STR) // one hvec buffer in words
#define AS    __HIP_MEMORY_SCOPE_AGENT

typedef unsigned long long u64;

#define LOG2E  1.44269504088896340736f

// opaque register pin (keeps one-time loads from being rematerialized)
#define KEEP4(v) asm volatile("" : "+v"(v.x), "+v"(v.y), "+v"(v.z), "+v"(v.w))

__device__ __forceinline__ float sigf(float x){
  return __builtin_amdgcn_rcpf(1.0f + __builtin_amdgcn_exp2f(-LOG2E * x));
}
__device__ __forceinline__ float tanhf_fast(float x){
  float e = __builtin_amdgcn_exp2f(2.0f * LOG2E * x);
  return 1.0f - 2.0f * __builtin_amdgcn_rcpf(e + 1.0f);
}
__device__ __forceinline__ float dot4(float4 a, float4 b){
  return a.x*b.x + a.y*b.y + a.z*b.z + a.w*b.w;
}

__global__ __launch_bounds__(NT, 1) void lstm2_kernel(
    const float* __restrict__ input,
    const float* __restrict__ Wih1, const float* __restrict__ Whh1,
    const float* __restrict__ bih1, const float* __restrict__ bhh1,
    const float* __restrict__ Wih2, const float* __restrict__ Whh2,
    const float* __restrict__ bih2, const float* __restrict__ bhh2,
    const float* __restrict__ Wlin, const float* __restrict__ blin,
    float* __restrict__ out, float* __restrict__ ws)
{
  // hvec buffer b (b=0/1), chunk c (c=0..3) at words [b*HVS + c*STR, +256):
  //   c0: h1 units {8w..8w+3} of WG w at word 4w   c1: h1 units {8w+4..8w+7}
  //   c2: h2 units {8w..8w+3}                      c3: h2 units {8w+4..8w+7}
  __shared__ __align__(16) float hvec[2*HVS];
  __shared__ __align__(16) float xrow[TT];

  float* comm = ws;             // [2][G][LINEF]

  const int t  = threadIdx.x;
  const int wg = blockIdx.x;
  const int rg = t >> 6;        // wave id 0..7 == local unit index
  const int sg = t & 63;        // lane

  ((float2*)xrow)[t] = ((const float2*)(input + 255*TT))[t];

  // ---- weight preload: wave rg owns L1 unit wg*8+rg and L2 unit wg*8+rg.
  // Gate q row: R = q*512 + wg*8 + rg. Lane sg covers cols [8sg, 8sg+8).
  float4 w1[4][2], w2[4][4];
  #pragma unroll
  for (int k=0;k<4;k++){
    const int R = k*HD + wg*8 + rg;
    const float* pa = Whh1 + R*HD + sg*8;
    w1[k][0] = *(const float4*)(pa);
    w1[k][1] = *(const float4*)(pa+4);
    const float* pb = Wih2 + R*HD + sg*8;
    const float* pc = Whh2 + R*HD + sg*8;
    w2[k][0] = *(const float4*)(pb);
    w2[k][1] = *(const float4*)(pb+4);
    w2[k][2] = *(const float4*)(pc);
    w2[k][3] = *(const float4*)(pc+4);
  }
  #pragma unroll
  for (int k=0;k<4;k++){
    KEEP4(w1[k][0]); KEEP4(w1[k][1]);
    KEEP4(w2[k][0]); KEEP4(w2[k][1]); KEEP4(w2[k][2]); KEEP4(w2[k][3]);
  }

  // per-wave combine lanes: sg==0 -> L1 unit wg*8+rg (holds c1); sg==1 -> L2
  float bias[4]={0,0,0,0}, wx[4]={0,0,0,0};
  float cst  = 0.f;     // persistent cell state (lane 0: c1, lane 1: c2)
  float hcur = 0.f;     // last h this lane produced (re-published every tick)
  if (sg < 2){
    #pragma unroll
    for (int q=0;q<4;q++){
      const int R = q*HD + wg*8 + rg;
      if (sg == 0){ bias[q] = bih1[R] + bhh1[R]; wx[q] = Wih1[R]; }
      else        { bias[q] = bih2[R] + bhh2[R]; }
    }
  }
  // Wlin fragment per lane (same for every wave; used by redundant computeO)
  const float4 wl0 = *(const float4*)(Wlin + sg*8);
  const float4 wl1 = *(const float4*)(Wlin + sg*8 + 4);
  const float blin0 = blin[0];

  // ---- consume tick g: thread t polls pairs {2j,2j+1} of line w=t>>3 ----
  auto poll_stage = [&](unsigned g){
    const int w = t >> 3, j = t & 7;
    const u64* dq = (const u64*)(comm + (g & 1u)*SLOTF + w*LINEF) + 2*j;
    u64 q0, q1;
    do {
      q0 = __hip_atomic_load(dq,     __ATOMIC_RELAXED, AS);
      q1 = __hip_atomic_load(dq + 1, __ATOMIC_RELAXED, AS);
    } while ((unsigned)(q0 >> 32) != g || (unsigned)(q1 >> 32) != g);
    const int c  = j >> 1;
    const int wd = (int)(g & 1u)*HVS + c*STR + 4*w + 2*(j & 1);
    float2 fv;
    fv.x = __builtin_bit_cast(float, (unsigned)q0);
    fv.y = __builtin_bit_cast(float, (unsigned)q1);
    *(float2*)(hvec + wd) = fv;
    __syncthreads();
  };

  // ---- dots + in-wave reduce-scatter; returns k1 (all lanes hold full sums:
  // lane m holds value j(m&7), j(m)=(m&1)*4+(m&2)+((m>>2)&1);
  // values 0..3 = L1 gates i,f,g,o of unit wg*8+rg; 4..7 = L2 gates) ----
  auto dots_reduce = [&](unsigned g)->float{
    const float* hb = hvec + (g & 1u)*HVS;
    const float4 c0 = ((const float4*)(hb + 0*STR))[sg];
    const float4 c1 = ((const float4*)(hb + 1*STR))[sg];
    const float4 c2 = ((const float4*)(hb + 2*STR))[sg];
    const float4 c3 = ((const float4*)(hb + 3*STR))[sg];
    float v[8];
    #pragma unroll
    for (int k=0;k<4;k++){
      v[k]   = dot4(w1[k][0],c0) + dot4(w1[k][1],c1);
      v[4+k] = dot4(w2[k][0],c0) + dot4(w2[k][1],c1)
             + dot4(w2[k][2],c2) + dot4(w2[k][3],c3);
    }
    const int b0 = sg & 1, b1 = (sg>>1)&1, b2 = (sg>>2)&1;
    float k4[4];
    #pragma unroll
    for (int k=0;k<4;k++){
      float x = b0 ? v[k] : v[k+4];
      float y = __shfl_xor(x, 1, 64);
      k4[k] = (b0 ? v[k+4] : v[k]) + y;
    }
    float k2[2];
    #pragma unroll
    for (int k=0;k<2;k++){
      float x = b1 ? k4[k] : k4[k+2];
      float y = __shfl_xor(x, 2, 64);
      k2[k] = (b1 ? k4[k+2] : k4[k]) + y;
    }
    float k1;
    {
      float x = b2 ? k2[0] : k2[1];
      float y = __shfl_xor(x, 4, 64);
      k1 = (b2 ? k2[1] : k2[0]) + y;
    }
    k1 += __shfl_xor(k1, 8, 64);
    k1 += __shfl_xor(k1, 16, 64);
    k1 += __shfl_xor(k1, 32, 64);
    return k1;
  };

  // ---- per-wave tail: gather own gates, apply, publish 2 pairs for g+1 ----
  // value v=r*4+q lives at lane r + 2*(q>>1) + 4*(q&1): srcs r, r+4, r+2, r+6.
  auto tick_tail = [&](unsigned g, bool d1, bool d2, float xv, float k1){
    const int r = sg & 1;
    float pi = __shfl(k1, r,     64);
    float pf = __shfl(k1, r + 4, 64);
    float pg = __shfl(k1, r + 2, 64);
    float po = __shfl(k1, r + 6, 64);
    if (sg < 2){
      const bool act = (r == 0) ? d1 : d2;
      if (act){
        if (r == 0){
          pi += xv*wx[0] + bias[0];
          pf += xv*wx[1] + bias[1];
          pg += xv*wx[2] + bias[2];
          po += xv*wx[3] + bias[3];
        } else {
          pi += bias[0]; pf += bias[1]; pg += bias[2]; po += bias[3];
        }
        cst  = sigf(pf)*cst + sigf(pi)*tanhf_fast(pg);
        hcur = sigf(po)*tanhf_fast(cst);
      }
      u64 pr = ((u64)(g + 1u) << 32) | (u64)__builtin_bit_cast(unsigned, hcur);
      u64* nb = (u64*)(comm + ((g+1u) & 1u)*SLOTF + wg*LINEF);
      __hip_atomic_store(nb + (r ? 8 + rg : rg), pr, __ATOMIC_RELAXED, AS);
    }
  };

  // o = Wlin.h2 + blin, computed redundantly by EVERY wave (no sync needed)
  auto computeO = [&](unsigned g)->float{
    const float* hb = hvec + (g & 1u)*HVS;
    float s = dot4(wl0, ((const float4*)(hb + 2*STR))[sg])
            + dot4(wl1, ((const float4*)(hb + 3*STR))[sg]);
    #pragma unroll
    for (int m=1;m<64;m<<=1) s += __shfl_xor(s, m, 64);
    return s + blin0;
  };

  unsigned g = 0;

  // ---- teacher: tick g computes L1 step g || L2 step g-1 ----
  for (int tk=0; tk<TT; ++tk, ++g){
    poll_stage(g);                         // hvec = [h1_{g-1} | h2_{g-2}]
    const float xv = xrow[tk];
    const float k1 = dots_reduce(g);
    tick_tail(g, true, tk >= 1, xv, k1);   // publish [h1_g | h2_{g-1}]
  }

  // ---- drain: L2 step 1023 ----
  poll_stage(g);                           // [h1_1023 | h2_1022]
  {
    const float k1 = dots_reduce(g);
    tick_tail(g, false, true, 0.f, k1);    // publish [h1_1023 | h2_1023]
  }
  ++g;

  // ---- AR: steps s = 1024..1086, 2 ticks each ----
  for (int s=TT; s<TT+PRED-1; ++s){
    poll_stage(g);                         // [h1_{s-1} | h2_{s-1}]
    const float xv = computeO(g);          // o_{s-1}, all lanes
    if (wg == 0 && t == 0) out[s - TT] = xv;
    float k1 = dots_reduce(g);
    tick_tail(g, true, false, xv, k1);     // publish [h1_s | h2_{s-1}]
    ++g;

    poll_stage(g);                         // [h1_s | h2_{s-1}]
    k1 = dots_reduce(g);
    tick_tail(g, false, true, 0.f, k1);    // publish [h1_s | h2_s]
    ++g;
  }

  // ---- final output o_1086 ----
  poll_stage(g);                           // [h1_1086 | h2_1086]
  const float xv = computeO(g);
  if (wg == 0 && t == 0) out[PRED - 1] = xv;
}

extern "C" void kernel_launch(void* const* d_in, const int* in_sizes, int n_in,
                              void* d_out, int out_size, void* d_ws, size_t ws_size,
                              hipStream_t stream) {
  const float* input = (const float*)d_in[0];
  // d_in[1] = pred_len (fixed 64, baked in)
  const float* Wih1 = (const float*)d_in[2];
  const float* Whh1 = (const float*)d_in[3];
  const float* bih1 = (const float*)d_in[4];
  const float* bhh1 = (const float*)d_in[5];
  const float* Wih2 = (const float*)d_in[6];
  const float* Whh2 = (const float*)d_in[7];
  const float* bih2 = (const float*)d_in[8];
  const float* bhh2 = (const float*)d_in[9];
  const float* Wlin = (const float*)d_in[10];
  const float* blin = (const float*)d_in[11];

  // zero comm: u64 zero pairs == (gen 0, h=0.0f) -> valid initial state
  hipMemsetAsync(d_ws, 0, 2 * SLOTF * sizeof(float), stream);

  lstm2_kernel<<<dim3(G), dim3(NT), 0, stream>>>(
      input, Wih1, Whh1, bih1, bhh1, Wih2, Whh2, bih2, bhh2, Wlin, blin,
      (float*)d_out, (float*)d_ws);
}

// Round 8
// 2488.103 us; speedup vs baseline: 1.4816x; 1.4816x over previous
//
#include <hip/hip_runtime.h>
#include <math.h>

// 2-layer LSTM (H=512), T=1024 teacher steps + 64 AR steps; only batch row 255
// reaches the output -> single-sequence LSTM. Weights register-resident across
// 64 persistent WGs. Per-tick all-to-all h exchange via SELF-VALIDATING pairs:
// each published value is a u64 (gen<<32 | bitcast(h)); a WG's line is 16
// pairs = 128 B, published by 16 lanes of wave 0 in ONE wave-wide atomic store
// burst (R7 proved distributing publication across waves quadruples write
// traffic and gates consumers on the slowest wave: 2065 -> 3686 us. Reverted.)
// Consumers: all 512 threads spin on relaxed b64 atomic loads (8 lanes/line,
// 2 pairs/lane) until gen fields == g -> detection and data in ONE IC
// round-trip. R8: polling is SOFTWARE-PIPELINED 3 deep (shift register of
// speculative load-pairs) so IC samples land every ~RT/3 instead of every RT,
// cutting expected detect-after-visible from ~RT to ~RT/2 + RT/6.
// 8B atomicity forbids torn reads; slot-reuse safe by barrier-ordered
// value-dependency causality. Intra-WG: wave-internal shuffle reduce-scatter
// -> 8 floats/wave to LDS -> wave 0 applies gates (fast v_exp/v_rcp
// sigmoid+tanh) and publishes. 2 __syncthreads per tick.

#define G     64      // workgroups
#define NT    512     // threads/wg
#define HD    512     // hidden
#define TT    1024    // teacher steps
#define PRED  64      // prediction length
#define LINEF 64      // floats per comm line slot (256 B); pairs in words 0..31
#define SLOTF (G*LINEF)
#define STR   264     // hvec chunk stride in words (256 data + 8 pad banks)
#define AS    __HIP_MEMORY_SCOPE_AGENT

typedef unsigned long long u64;

#define LOG2E  1.44269504088896340736f

// opaque register pin (keeps one-time loads from being rematerialized)
#define KEEP4(v) asm volatile("" : "+v"(v.x), "+v"(v.y), "+v"(v.z), "+v"(v.w))

__device__ __forceinline__ float sigf(float x){
  return __builtin_amdgcn_rcpf(1.0f + __builtin_amdgcn_exp2f(-LOG2E * x));
}
__device__ __forceinline__ float tanhf_fast(float x){
  float e = __builtin_amdgcn_exp2f(2.0f * LOG2E * x);
  return 1.0f - 2.0f * __builtin_amdgcn_rcpf(e + 1.0f);
}
__device__ __forceinline__ float dot4(float4 a, float4 b){
  return a.x*b.x + a.y*b.y + a.z*b.z + a.w*b.w;
}

__global__ __launch_bounds__(NT, 1) void lstm2_kernel(
    const float* __restrict__ input,
    const float* __restrict__ Wih1, const float* __restrict__ Whh1,
    const float* __restrict__ bih1, const float* __restrict__ bhh1,
    const float* __restrict__ Wih2, const float* __restrict__ Whh2,
    const float* __restrict__ bih2, const float* __restrict__ bhh2,
    const float* __restrict__ Wlin, const float* __restrict__ blin,
    float* __restrict__ out, float* __restrict__ ws)
{
  // hvec chunk c (c=0..3) = words [c*STR, c*STR+256):
  //   c0: h1 units {8w..8w+3} of WG w at word 4w   c1: h1 units {8w+4..8w+7}
  //   c2: h2 units {8w..8w+3}                      c3: h2 units {8w+4..8w+7}
  __shared__ __align__(16) float hvec[4*STR];
  __shared__ __align__(16) float xrow[TT];
  __shared__ float pre[64];     // [0..31]=L1 rows (gate q*8+unit u), [32..63]=L2

  float* comm = ws;             // [2][G][LINEF]

  const int t  = threadIdx.x;
  const int wg = blockIdx.x;
  const int rg = t >> 6;        // wave id 0..7
  const int sg = t & 63;        // lane

  ((float2*)xrow)[t] = ((const float2*)(input + 255*TT))[t];

  // ---- weight preload: wg owns hidden units [wg*8, wg*8+8) of both layers.
  // Row r = rg*4+k (r in 0..31: gate q=r>>3, unit u=r&7) -> global row
  // q*512 + wg*8 + u. Lane sg covers cols [8sg, 8sg+8).
  float4 w1[4][2], w2[4][4];
  #pragma unroll
  for (int k=0;k<4;k++){
    const int r = rg*4 + k;
    const int R = (r>>3)*HD + wg*8 + (r&7);
    const float* pa = Whh1 + R*HD + sg*8;
    w1[k][0] = *(const float4*)(pa);
    w1[k][1] = *(const float4*)(pa+4);
    const float* pb = Wih2 + R*HD + sg*8;
    const float* pc = Whh2 + R*HD + sg*8;
    w2[k][0] = *(const float4*)(pb);
    w2[k][1] = *(const float4*)(pb+4);
    w2[k][2] = *(const float4*)(pc);
    w2[k][3] = *(const float4*)(pc+4);
  }
  #pragma unroll
  for (int k=0;k<4;k++){
    KEEP4(w1[k][0]); KEEP4(w1[k][1]);
    KEEP4(w2[k][0]); KEEP4(w2[k][1]); KEEP4(w2[k][2]); KEEP4(w2[k][3]);
  }

  // combine lanes (wave 0): t<8 -> L1 unit t; t in [8,16) -> L2 unit t-8
  float bias[4]={0,0,0,0}, wx[4]={0,0,0,0};
  float cst  = 0.f;     // persistent cell state
  float hcur = 0.f;     // last h this lane produced (re-published every tick)
  if (t < 8){
    #pragma unroll
    for (int q=0;q<4;q++){
      int R = q*HD + wg*8 + t;
      bias[q] = bih1[R] + bhh1[R];
      wx[q]   = Wih1[R];
    }
  } else if (t < 16){
    #pragma unroll
    for (int q=0;q<4;q++){
      int R = q*HD + wg*8 + (t-8);
      bias[q] = bih2[R] + bhh2[R];
    }
  }
  float4 wl0={0,0,0,0}, wl1={0,0,0,0};
  if (t < 64){
    wl0 = *(const float4*)(Wlin + t*8);
    wl1 = *(const float4*)(Wlin + t*8 + 4);
  }
  const float blin0 = blin[0];

  // ---- consume tick g: thread t polls pairs {2j,2j+1} of line w=t>>3,
  // 3-deep software-pipelined: 3 speculative load-pairs in flight; steady-
  // state IC sampling period ~RT/3 instead of ~RT.
  auto poll_stage = [&](unsigned g){
    const int w = t >> 3, j = t & 7;
    const u64* dq = (const u64*)(comm + (g & 1u)*SLOTF + w*LINEF) + 2*j;
    u64 a0 = __hip_atomic_load(dq,     __ATOMIC_RELAXED, AS);
    u64 a1 = __hip_atomic_load(dq + 1, __ATOMIC_RELAXED, AS);
    u64 b0 = __hip_atomic_load(dq,     __ATOMIC_RELAXED, AS);
    u64 b1 = __hip_atomic_load(dq + 1, __ATOMIC_RELAXED, AS);
    u64 c0 = __hip_atomic_load(dq,     __ATOMIC_RELAXED, AS);
    u64 c1 = __hip_atomic_load(dq + 1, __ATOMIC_RELAXED, AS);
    while ((unsigned)(a0 >> 32) != g || (unsigned)(a1 >> 32) != g){
      a0 = b0; a1 = b1;
      b0 = c0; b1 = c1;
      c0 = __hip_atomic_load(dq,     __ATOMIC_RELAXED, AS);
      c1 = __hip_atomic_load(dq + 1, __ATOMIC_RELAXED, AS);
    }
    // pair i of line w: i<8 -> h1 unit w*8+i ; i>=8 -> h2 unit w*8+(i-8)
    // chunk cidx = (2j)>>2 = j>>1; word-in-chunk = 4w + 2*(j&1)
    const int cidx = j >> 1;
    const int wd   = cidx*STR + 4*w + 2*(j & 1);
    float2 fv;
    fv.x = __builtin_bit_cast(float, (unsigned)a0);
    fv.y = __builtin_bit_cast(float, (unsigned)a1);
    *(float2*)(hvec + wd) = fv;
    __syncthreads();
  };

  // ---- dots + wave-internal reduce-scatter; writes 8 row-sums/wave to pre ----
  auto dots_reduce = [&](){
    const float4 c0 = ((const float4*)(hvec + 0*STR))[sg];
    const float4 c1 = ((const float4*)(hvec + 1*STR))[sg];
    const float4 c2 = ((const float4*)(hvec + 2*STR))[sg];
    const float4 c3 = ((const float4*)(hvec + 3*STR))[sg];
    float v[8];
    #pragma unroll
    for (int k=0;k<4;k++){
      v[k]   = dot4(w1[k][0],c0) + dot4(w1[k][1],c1);
      v[4+k] = dot4(w2[k][0],c0) + dot4(w2[k][1],c1)
             + dot4(w2[k][2],c2) + dot4(w2[k][3],c3);
    }
    const int b0 = sg & 1, b1 = (sg>>1)&1, b2 = (sg>>2)&1;
    float k4[4];
    #pragma unroll
    for (int k=0;k<4;k++){
      float x = b0 ? v[k] : v[k+4];
      float y = __shfl_xor(x, 1, 64);
      k4[k] = (b0 ? v[k+4] : v[k]) + y;
    }
    float k2[2];
    #pragma unroll
    for (int k=0;k<2;k++){
      float x = b1 ? k4[k] : k4[k+2];
      float y = __shfl_xor(x, 2, 64);
      k2[k] = (b1 ? k4[k+2] : k4[k]) + y;
    }
    float k1;
    {
      float x = b2 ? k2[0] : k2[1];
      float y = __shfl_xor(x, 4, 64);
      k1 = (b2 ? k2[1] : k2[0]) + y;
    }
    k1 += __shfl_xor(k1, 8, 64);
    k1 += __shfl_xor(k1, 16, 64);
    k1 += __shfl_xor(k1, 32, 64);
    if (sg < 8){
      const int j = b0*4 + b1*2 + b2;   // value index this lane holds
      if (j < 4) pre[rg*4 + j]        = k1;   // L1 row rg*4+j
      else       pre[32 + rg*4 + j-4] = k1;   // L2 row rg*4+(j-4)
    }
  };

  // ---- tail (wave 0): gate math + publish self-validating pairs for g+1 ----
  auto tail = [&](unsigned g, bool d1, bool d2, float xv){
    if (rg == 0){
      const float rsum = pre[t];
      const int u  = t & 7;
      const int s0 = (t < 8) ? t : (32 + u);   // lanes >=16: don't-care
      float pi = __shfl(rsum, s0,      64);
      float pf = __shfl(rsum, s0 + 8,  64);
      float pg = __shfl(rsum, s0 + 16, 64);
      float po = __shfl(rsum, s0 + 24, 64);
      const bool act = (t < 8) ? d1 : ((t < 16) ? d2 : false);
      if (act){
        if (t < 8){
          pi += xv*wx[0] + bias[0];
          pf += xv*wx[1] + bias[1];
          pg += xv*wx[2] + bias[2];
          po += xv*wx[3] + bias[3];
        } else {
          pi += bias[0]; pf += bias[1]; pg += bias[2]; po += bias[3];
        }
        cst  = sigf(pf)*cst + sigf(pi)*tanhf_fast(pg);
        hcur = sigf(po)*tanhf_fast(cst);
      }
      if (t < 16){
        u64 pr = ((u64)(g + 1u) << 32) | (u64)__builtin_bit_cast(unsigned, hcur);
        u64* nb = (u64*)(comm + ((g+1u) & 1u)*SLOTF + wg*LINEF);
        __hip_atomic_store(nb + t, pr, __ATOMIC_RELAXED, AS);
      }
    }
  };

  // o = Wlin . h2 + blin from hvec chunks 2/3; result in ALL wave-0 lanes
  auto computeO = [&](int oi, float& xv){
    if (rg == 0){
      float s = dot4(wl0, ((const float4*)(hvec + 2*STR))[t])
              + dot4(wl1, ((const float4*)(hvec + 3*STR))[t]);
      #pragma unroll
      for (int m=1;m<64;m<<=1) s += __shfl_xor(s, m, 64);
      xv = s + blin0;
      if (wg == 0 && t == 0) out[oi] = xv;
    }
  };

  __syncthreads();   // xrow staged

  unsigned g = 0;

  // ---- teacher: tick g computes L1 step g || L2 step g-1 ----
  for (int tk=0; tk<TT; ++tk, ++g){
    poll_stage(g);                       // hvec = [h1_{g-1} | h2_{g-2}]
    dots_reduce();
    __syncthreads();
    tail(g, true, tk >= 1, xrow[tk]);    // publish [h1_g | h2_{g-1}] pairs
  }

  // ---- drain: L2 step 1023 ----
  poll_stage(g);                         // [h1_1023 | h2_1022]
  dots_reduce();
  __syncthreads();
  tail(g, false, true, 0.f);             // publish [h1_1023 | h2_1023]
  ++g;

  // ---- AR: steps s = 1024..1086, 2 ticks each ----
  for (int s=TT; s<TT+PRED-1; ++s){
    poll_stage(g);                       // [h1_{s-1} | h2_{s-1}]
    float xv = 0.f;
    computeO(s - TT, xv);                // emit out[s-TT] (o_{s-1})
    dots_reduce();
    __syncthreads();
    tail(g, true, false, xv);            // publish [h1_s | h2_{s-1}]
    ++g;

    poll_stage(g);                       // [h1_s | h2_{s-1}]
    dots_reduce();
    __syncthreads();
    tail(g, false, true, 0.f);           // publish [h1_s | h2_s]
    ++g;
  }

  // ---- final output o_1086 ----
  poll_stage(g);                         // [h1_1086 | h2_1086]
  float xv;
  computeO(PRED - 1, xv);
}

extern "C" void kernel_launch(void* const* d_in, const int* in_sizes, int n_in,
                              void* d_out, int out_size, void* d_ws, size_t ws_size,
                              hipStream_t stream) {
  const float* input = (const float*)d_in[0];
  // d_in[1] = pred_len (fixed 64, baked in)
  const float* Wih1 = (const float*)d_in[2];
  const float* Whh1 = (const float*)d_in[3];
  const float* bih1 = (const float*)d_in[4];
  const float* bhh1 = (const float*)d_in[5];
  const float* Wih2 = (const float*)d_in[6];
  const float* Whh2 = (const float*)d_in[7];
  const float* bih2 = (const float*)d_in[8];
  const float* bhh2 = (const float*)d_in[9];
  const float* Wlin = (const float*)d_in[10];
  const float* blin = (const float*)d_in[11];

  // zero comm: u64 zero pairs == (gen 0, h=0.0f) -> valid initial state
  hipMemsetAsync(d_ws, 0, 2 * SLOTF * sizeof(float), stream);

  lstm2_kernel<<<dim3(G), dim3(NT), 0, stream>>>(
      input, Wih1, Whh1, bih1, bhh1, Wih2, Whh2, bih2, bhh2, Wlin, blin,
      (float*)d_out, (float*)d_ws);
}

// Round 9
// 2263.005 us; speedup vs baseline: 1.6289x; 1.0995x over previous
//
#include <hip/hip_runtime.h>
#include <math.h>

// 2-layer LSTM (H=512), T=1024 teacher steps + 64 AR steps; only batch row 255
// reaches the output -> single-sequence LSTM. Weights register-resident across
// 64 persistent WGs. Per-tick all-to-all h exchange via SELF-VALIDATING pairs:
// each published value is a u64 (gen<<32 | bitcast(h)). R9: each WG's 16
// pairs are published to 4 REPLICA blocks (256 B apart) in ONE wave-wide
// atomic store burst from wave 0 (lane l -> pair l&15, replica l>>4), and
// consumer WG wg polls only replica wg&3 -> 128 pollers per 128B line instead
// of 512 (R6's whole exchange lived on 64 cache lines; per-line request
// serialization at the IC slice was the unexplained ~0.7us/tick).
// R8 lesson: software-pipelined polling regresses (compiler drains vmcnt(0),
// checking 2-RT-stale samples) -> simple 2-load poll loop kept.
// R7 lesson: distributing publication across 8 waves gates consumers on the
// slowest wave -> centralized wave-0 publish kept.
// 8B atomicity forbids torn reads; slot-reuse safe by barrier-ordered
// value-dependency causality per (consumer, replica) pair. Intra-WG:
// wave-internal shuffle reduce-scatter -> 8 floats/wave to LDS -> wave 0
// applies gates (fast v_exp/v_rcp sigmoid+tanh) and publishes. 2 syncs/tick.

#define G     64      // workgroups
#define NT    512     // threads/wg
#define HD    512     // hidden
#define TT    1024    // teacher steps
#define PRED  64      // prediction length
#define REP   4       // publication replicas
#define RBLK  32      // u64 per replica block (256 B: 16 data pairs + pad)
#define LBLK  (REP*RBLK)   // u64 per line block (4 replicas)
#define SLOTU (G*LBLK)     // u64 per parity slot
#define STR   264     // hvec chunk stride in words (256 data + 8 pad banks)
#define AS    __HIP_MEMORY_SCOPE_AGENT

typedef unsigned long long u64;

#define LOG2E  1.44269504088896340736f

// opaque register pin (keeps one-time loads from being rematerialized)
#define KEEP4(v) asm volatile("" : "+v"(v.x), "+v"(v.y), "+v"(v.z), "+v"(v.w))

__device__ __forceinline__ float sigf(float x){
  return __builtin_amdgcn_rcpf(1.0f + __builtin_amdgcn_exp2f(-LOG2E * x));
}
__device__ __forceinline__ float tanhf_fast(float x){
  float e = __builtin_amdgcn_exp2f(2.0f * LOG2E * x);
  return 1.0f - 2.0f * __builtin_amdgcn_rcpf(e + 1.0f);
}
__device__ __forceinline__ float dot4(float4 a, float4 b){
  return a.x*b.x + a.y*b.y + a.z*b.z + a.w*b.w;
}

__global__ __launch_bounds__(NT, 1) void lstm2_kernel(
    const float* __restrict__ input,
    const float* __restrict__ Wih1, const float* __restrict__ Whh1,
    const float* __restrict__ bih1, const float* __restrict__ bhh1,
    const float* __restrict__ Wih2, const float* __restrict__ Whh2,
    const float* __restrict__ bih2, const float* __restrict__ bhh2,
    const float* __restrict__ Wlin, const float* __restrict__ blin,
    float* __restrict__ out, float* __restrict__ ws)
{
  // hvec chunk c (c=0..3) = words [c*STR, c*STR+256):
  //   c0: h1 units {8w..8w+3} of WG w at word 4w   c1: h1 units {8w+4..8w+7}
  //   c2: h2 units {8w..8w+3}                      c3: h2 units {8w+4..8w+7}
  __shared__ __align__(16) float hvec[4*STR];
  __shared__ __align__(16) float xrow[TT];
  __shared__ float pre[64];     // [0..31]=L1 rows (gate q*8+unit u), [32..63]=L2

  u64* commu = (u64*)ws;        // [2][G][REP][RBLK]

  const int t  = threadIdx.x;
  const int wg = blockIdx.x;
  const int rg = t >> 6;        // wave id 0..7
  const int sg = t & 63;        // lane

  ((float2*)xrow)[t] = ((const float2*)(input + 255*TT))[t];

  // ---- weight preload: wg owns hidden units [wg*8, wg*8+8) of both layers.
  // Row r = rg*4+k (r in 0..31: gate q=r>>3, unit u=r&7) -> global row
  // q*512 + wg*8 + u. Lane sg covers cols [8sg, 8sg+8).
  float4 w1[4][2], w2[4][4];
  #pragma unroll
  for (int k=0;k<4;k++){
    const int r = rg*4 + k;
    const int R = (r>>3)*HD + wg*8 + (r&7);
    const float* pa = Whh1 + R*HD + sg*8;
    w1[k][0] = *(const float4*)(pa);
    w1[k][1] = *(const float4*)(pa+4);
    const float* pb = Wih2 + R*HD + sg*8;
    const float* pc = Whh2 + R*HD + sg*8;
    w2[k][0] = *(const float4*)(pb);
    w2[k][1] = *(const float4*)(pb+4);
    w2[k][2] = *(const float4*)(pc);
    w2[k][3] = *(const float4*)(pc+4);
  }
  #pragma unroll
  for (int k=0;k<4;k++){
    KEEP4(w1[k][0]); KEEP4(w1[k][1]);
    KEEP4(w2[k][0]); KEEP4(w2[k][1]); KEEP4(w2[k][2]); KEEP4(w2[k][3]);
  }

  // combine lanes (wave 0): t<8 -> L1 unit t; t in [8,16) -> L2 unit t-8
  float bias[4]={0,0,0,0}, wx[4]={0,0,0,0};
  float cst  = 0.f;     // persistent cell state
  float hcur = 0.f;     // last h this lane produced (re-published every tick)
  if (t < 8){
    #pragma unroll
    for (int q=0;q<4;q++){
      int R = q*HD + wg*8 + t;
      bias[q] = bih1[R] + bhh1[R];
      wx[q]   = Wih1[R];
    }
  } else if (t < 16){
    #pragma unroll
    for (int q=0;q<4;q++){
      int R = q*HD + wg*8 + (t-8);
      bias[q] = bih2[R] + bhh2[R];
    }
  }
  float4 wl0={0,0,0,0}, wl1={0,0,0,0};
  if (t < 64){
    wl0 = *(const float4*)(Wlin + t*8);
    wl1 = *(const float4*)(Wlin + t*8 + 4);
  }
  const float blin0 = blin[0];

  // ---- consume tick g: thread t polls pairs {2j,2j+1} of line w=t>>3,
  // replica wg&3. Simple 2-load spin (R8: deeper pipelining regresses).
  auto poll_stage = [&](unsigned g){
    const int w = t >> 3, j = t & 7;
    const u64* dq = commu + (g & 1u)*SLOTU + w*LBLK + (wg & (REP-1))*RBLK + 2*j;
    u64 q0, q1;
    do {
      q0 = __hip_atomic_load(dq,     __ATOMIC_RELAXED, AS);
      q1 = __hip_atomic_load(dq + 1, __ATOMIC_RELAXED, AS);
    } while ((unsigned)(q0 >> 32) != g || (unsigned)(q1 >> 32) != g);
    // pair i of line w: i<8 -> h1 unit w*8+i ; i>=8 -> h2 unit w*8+(i-8)
    // chunk cidx = (2j)>>2 = j>>1; word-in-chunk = 4w + 2*(j&1)
    const int cidx = j >> 1;
    const int wd   = cidx*STR + 4*w + 2*(j & 1);
    float2 fv;
    fv.x = __builtin_bit_cast(float, (unsigned)q0);
    fv.y = __builtin_bit_cast(float, (unsigned)q1);
    *(float2*)(hvec + wd) = fv;
    __syncthreads();
  };

  // ---- dots + wave-internal reduce-scatter; writes 8 row-sums/wave to pre ----
  auto dots_reduce = [&](){
    const float4 c0 = ((const float4*)(hvec + 0*STR))[sg];
    const float4 c1 = ((const float4*)(hvec + 1*STR))[sg];
    const float4 c2 = ((const float4*)(hvec + 2*STR))[sg];
    const float4 c3 = ((const float4*)(hvec + 3*STR))[sg];
    float v[8];
    #pragma unroll
    for (int k=0;k<4;k++){
      v[k]   = dot4(w1[k][0],c0) + dot4(w1[k][1],c1);
      v[4+k] = dot4(w2[k][0],c0) + dot4(w2[k][1],c1)
             + dot4(w2[k][2],c2) + dot4(w2[k][3],c3);
    }
    const int b0 = sg & 1, b1 = (sg>>1)&1, b2 = (sg>>2)&1;
    float k4[4];
    #pragma unroll
    for (int k=0;k<4;k++){
      float x = b0 ? v[k] : v[k+4];
      float y = __shfl_xor(x, 1, 64);
      k4[k] = (b0 ? v[k+4] : v[k]) + y;
    }
    float k2[2];
    #pragma unroll
    for (int k=0;k<2;k++){
      float x = b1 ? k4[k] : k4[k+2];
      float y = __shfl_xor(x, 2, 64);
      k2[k] = (b1 ? k4[k+2] : k4[k]) + y;
    }
    float k1;
    {
      float x = b2 ? k2[0] : k2[1];
      float y = __shfl_xor(x, 4, 64);
      k1 = (b2 ? k2[1] : k2[0]) + y;
    }
    k1 += __shfl_xor(k1, 8, 64);
    k1 += __shfl_xor(k1, 16, 64);
    k1 += __shfl_xor(k1, 32, 64);
    if (sg < 8){
      const int j = b0*4 + b1*2 + b2;   // value index this lane holds
      if (j < 4) pre[rg*4 + j]        = k1;   // L1 row rg*4+j
      else       pre[32 + rg*4 + j-4] = k1;   // L2 row rg*4+(j-4)
    }
  };

  // ---- tail (wave 0): gate math + 4x-replicated publish for tick g+1.
  // Lane l stores pair l&15 into replica l>>4: one wave-wide store burst.
  auto tail = [&](unsigned g, bool d1, bool d2, float xv){
    if (rg == 0){
      const float rsum = pre[t];
      const int u  = t & 7;
      const int s0 = (t < 8) ? t : (32 + u);   // lanes >=16: don't-care
      float pi = __shfl(rsum, s0,      64);
      float pf = __shfl(rsum, s0 + 8,  64);
      float pg = __shfl(rsum, s0 + 16, 64);
      float po = __shfl(rsum, s0 + 24, 64);
      const bool act = (t < 8) ? d1 : ((t < 16) ? d2 : false);
      if (act){
        if (t < 8){
          pi += xv*wx[0] + bias[0];
          pf += xv*wx[1] + bias[1];
          pg += xv*wx[2] + bias[2];
          po += xv*wx[3] + bias[3];
        } else {
          pi += bias[0]; pf += bias[1]; pg += bias[2]; po += bias[3];
        }
        cst  = sigf(pf)*cst + sigf(pi)*tanhf_fast(pg);
        hcur = sigf(po)*tanhf_fast(cst);
      }
      // broadcast pair (t&15) to this lane, store to replica (t>>4)
      const float hsrc = __shfl(hcur, t & 15, 64);
      u64 pr = ((u64)(g + 1u) << 32) | (u64)__builtin_bit_cast(unsigned, hsrc);
      u64* nb = commu + ((g+1u) & 1u)*SLOTU + wg*LBLK + (t >> 4)*RBLK + (t & 15);
      __hip_atomic_store(nb, pr, __ATOMIC_RELAXED, AS);
    }
  };

  // o = Wlin . h2 + blin from hvec chunks 2/3; result in ALL wave-0 lanes
  auto computeO = [&](int oi, float& xv){
    if (rg == 0){
      float s = dot4(wl0, ((const float4*)(hvec + 2*STR))[t])
              + dot4(wl1, ((const float4*)(hvec + 3*STR))[t]);
      #pragma unroll
      for (int m=1;m<64;m<<=1) s += __shfl_xor(s, m, 64);
      xv = s + blin0;
      if (wg == 0 && t == 0) out[oi] = xv;
    }
  };

  __syncthreads();   // xrow staged

  unsigned g = 0;

  // ---- teacher: tick g computes L1 step g || L2 step g-1 ----
  for (int tk=0; tk<TT; ++tk, ++g){
    poll_stage(g);                       // hvec = [h1_{g-1} | h2_{g-2}]
    dots_reduce();
    __syncthreads();
    tail(g, true, tk >= 1, xrow[tk]);    // publish [h1_g | h2_{g-1}] pairs
  }

  // ---- drain: L2 step 1023 ----
  poll_stage(g);                         // [h1_1023 | h2_1022]
  dots_reduce();
  __syncthreads();
  tail(g, false, true, 0.f);             // publish [h1_1023 | h2_1023]
  ++g;

  // ---- AR: steps s = 1024..1086, 2 ticks each ----
  for (int s=TT; s<TT+PRED-1; ++s){
    poll_stage(g);                       // [h1_{s-1} | h2_{s-1}]
    float xv = 0.f;
    computeO(s - TT, xv);                // emit out[s-TT] (o_{s-1})
    dots_reduce();
    __syncthreads();
    tail(g, true, false, xv);            // publish [h1_s | h2_{s-1}]
    ++g;

    poll_stage(g);                       // [h1_s | h2_{s-1}]
    dots_reduce();
    __syncthreads();
    tail(g, false, true, 0.f);           // publish [h1_s | h2_s]
    ++g;
  }

  // ---- final output o_1086 ----
  poll_stage(g);                         // [h1_1086 | h2_1086]
  float xv;
  computeO(PRED - 1, xv);
}

extern "C" void kernel_launch(void* const* d_in, const int* in_sizes, int n_in,
                              void* d_out, int out_size, void* d_ws, size_t ws_size,
                              hipStream_t stream) {
  const float* input = (const float*)d_in[0];
  // d_in[1] = pred_len (fixed 64, baked in)
  const float* Wih1 = (const float*)d_in[2];
  const float* Whh1 = (const float*)d_in[3];
  const float* bih1 = (const float*)d_in[4];
  const float* bhh1 = (const float*)d_in[5];
  const float* Wih2 = (const float*)d_in[6];
  const float* Whh2 = (const float*)d_in[7];
  const float* bih2 = (const float*)d_in[8];
  const float* bhh2 = (const float*)d_in[9];
  const float* Wlin = (const float*)d_in[10];
  const float* blin = (const float*)d_in[11];

  // zero comm: u64 zero pairs == (gen 0, h=0.0f) -> valid initial state
  // 2 slots x 64 lines x 4 replicas x 256 B = 128 KiB
  hipMemsetAsync(d_ws, 0, (size_t)2 * SLOTU * sizeof(u64), stream);

  lstm2_kernel<<<dim3(G), dim3(NT), 0, stream>>>(
      input, Wih1, Whh1, bih1, bhh1, Wih2, Whh2, bih2, bhh2, Wlin, blin,
      (float*)d_out, (float*)d_ws);
}